// Round 12
// baseline (558.855 us; speedup 1.0000x reference)
//
#include <hip/hip_runtime.h>

#define N_NODES 50000
#define N_EDGES 800000
#define N_GRAPHS 256
#define HID 128
#define OUT_CH 10
#define BN_EPS 1e-5f

#define NBUCKET 98               // ceil(50000/512) buckets of 512 nodes
#define BCAP 10240               // per-bucket pair capacity (mean 8192, sd ~90)
#define BN_BLOCKS 1024           // k_bnstats grid

// ---------------- workspace layout (4-byte element offsets) ----------------
#define OFF_H       0            // bf16 H: 50000*128 ushort -> 3.2M f32 slots
#define OFF_BNPART  2937856      // 1024*256 f32 partials (dead Hb tail, rows 45904+)
#define OFF_CSRD    3200000      // 800,000 f32 (dinv[src] per CSR slot)
#define OFF_WBT     4000000      // 3 * 128*136 ushort = 26,112 f32 slots
#define OFF_AGG     6400000      // 6,400,000 f32; bucketBuf overlaps (build only)
#define OFF_ROWPTR  12850000     // 50,001 i32
#define OFF_CSR     12950004     // 800,000 i32
#define OFF_DINV    13750004     // 50,000 f32
#define OFF_BNCOEF  13800004     // 256 f32 (scale[128], shift[128])
#define OFF_BCNT    13833284     // NBUCKET i32
// bucketBuf: int2[NBUCKET*BCAP] at OFF_AGG (8 MB), used only pre-agg.
// BNPART: Hb rows 45904..50000 region, dead once k_agg consumed Hb;
// rewritten by bnstats, consumed by bnred before the next gemm rewrites Hb.

#define WBT_PITCH 136            // ushorts per row (128 + 8 pad)

typedef __attribute__((ext_vector_type(8))) short bf16x8;
typedef __attribute__((ext_vector_type(4))) float f32x4;

__device__ __forceinline__ ushort f2bf(float f) {
    union { float f; unsigned u; } v; v.f = f;
    unsigned r = v.u + 0x7FFFu + ((v.u >> 16) & 1u);   // RNE
    return (ushort)(r >> 16);
}
__device__ __forceinline__ float bf2f(unsigned u16) {
    return __uint_as_float(u16 << 16);
}

// ---------------- prep: zero bucket counters + W->bf16 transpose -----------
__global__ void k_prep(const float* __restrict__ W0, const float* __restrict__ W1,
                       const float* __restrict__ W2, ushort* __restrict__ Wbt,
                       int* __restrict__ bcnt) {
    int i = blockIdx.x * 256 + threadIdx.x;   // 0..49151
    if (blockIdx.x == 0 && threadIdx.x < NBUCKET) bcnt[threadIdx.x] = 0;
    if (i < 3 * 16384) {
        int layer = i / 16384, r = i - layer * 16384;
        const float* W = (layer == 0) ? W0 : (layer == 1) ? W1 : W2;
        int k = r >> 7, c = r & 127;
        Wbt[layer * 128 * WBT_PITCH + c * WBT_PITCH + k] = f2bf(W[r]);
    }
}

// ---------------- bucket edges by dst>>9 (block-reserved append) ----------
__global__ __launch_bounds__(256) void k_bucket(const int* __restrict__ ei,
                                                int* __restrict__ bcnt,
                                                int2* __restrict__ buf) {
    __shared__ int histL[NBUCKET], baseL[NBUCKET], curL[NBUCKET];
    int t = threadIdx.x;
    if (t < NBUCKET) histL[t] = 0;
    __syncthreads();
    const int stride = gridDim.x * 256;
    for (int i = blockIdx.x * 256 + t; i < N_EDGES; i += stride)
        atomicAdd(&histL[ei[N_EDGES + i] >> 9], 1);
    __syncthreads();
    if (t < NBUCKET) {
        baseL[t] = atomicAdd(&bcnt[t], histL[t]);
        curL[t] = 0;
    }
    __syncthreads();
    for (int i = blockIdx.x * 256 + t; i < N_EDGES; i += stride) {
        int s = ei[i];
        int d = ei[N_EDGES + i];
        int b = d >> 9;
        int p = baseL[b] + atomicAdd(&curL[b], 1);
        if (p < BCAP) buf[b * BCAP + p] = make_int2(s, d);
    }
}

// ---------------- per-bucket CSR build: hist, scan, direct scatter ---------
__global__ __launch_bounds__(512) void k_csrbuild(const int2* __restrict__ buf,
                                                  const int* __restrict__ bcnt,
                                                  int* __restrict__ rowptr,
                                                  int* __restrict__ csr,
                                                  float* __restrict__ dinv) {
    __shared__ int off[512];
    __shared__ int cur[512];
    __shared__ int ebase_s;
    int b = blockIdx.x, t = threadIdx.x;
    int node0 = b << 9;
    int cnt = bcnt[b];
    const int2* mybuf = buf + b * BCAP;

    if (t == 0) {
        int acc = 0;
        for (int i = 0; i < b; ++i) acc += bcnt[i];
        ebase_s = acc;
        if (b == NBUCKET - 1) rowptr[N_NODES] = acc + cnt;
    }
    off[t] = 0;
    __syncthreads();
    int ebase = ebase_s;
    for (int e = t; e < cnt; e += 512)
        atomicAdd(&off[mybuf[e].y - node0], 1);
    __syncthreads();
    int mydeg = off[t];
    for (int o = 1; o < 512; o <<= 1) {
        int x = (t >= o) ? off[t - o] : 0;
        __syncthreads();
        off[t] += x;
        __syncthreads();
    }
    int inc = off[t];
    cur[t] = ebase + inc - mydeg;
    int node = node0 + t;
    if (node < N_NODES) {
        rowptr[node] = ebase + inc - mydeg;
        dinv[node] = rsqrtf((float)(mydeg + 1));
    }
    __syncthreads();
    for (int e = t; e < cnt; e += 512) {
        int2 pr = mybuf[e];
        int p = atomicAdd(&cur[pr.y - node0], 1);
        csr[p] = pr.x;
    }
}

// ---------------- canonicalize: sort each segment ascending, fill csrd -----
__global__ __launch_bounds__(256) void k_sortseg(const int* __restrict__ rowptr,
                                                 int* __restrict__ csr,
                                                 const float* __restrict__ dinv,
                                                 float* __restrict__ csrd) {
    int wave = threadIdx.x >> 6, lane = threadIdx.x & 63;
    int v = blockIdx.x * 4 + wave;
    if (v >= N_NODES) return;
    int e0 = rowptr[v], deg = rowptr[v + 1] - e0;
    if (deg <= 64) {
        int val = (lane < deg) ? csr[e0 + lane] : 0x7FFFFFFF;
#pragma unroll
        for (int k = 2; k <= 64; k <<= 1)
#pragma unroll
            for (int j = k >> 1; j > 0; j >>= 1) {
                int other = __shfl_xor(val, j);
                bool up = ((lane & k) == 0);
                bool lower = ((lane & j) == 0);
                int mn = min(val, other), mx = max(val, other);
                val = (up == lower) ? mn : mx;
            }
        if (lane < deg) {
            csr[e0 + lane] = val;
            csrd[e0 + lane] = dinv[val];
        }
    } else {
        if (lane == 0) {
            for (int i = e0 + 1; i < e0 + deg; ++i) {
                int key = csr[i];
                int j = i - 1;
                while (j >= e0 && csr[j] > key) { csr[j + 1] = csr[j]; --j; }
                csr[j + 1] = key;
            }
        }
        for (int e = e0 + lane; e < e0 + deg; e += 64) csrd[e] = dinv[csr[e]];
    }
}

// ---------------- MFMA GEMM: Hb[n,128](bf16) = f(X)[n,128] @ W -------------
template <int BN>
__global__ __launch_bounds__(256) void k_gemm(const float* __restrict__ X,
                                              const ushort* __restrict__ Wbt,
                                              ushort* __restrict__ Hb,
                                              const float* __restrict__ coef,
                                              int nrows) {
    __shared__ __align__(16) ushort Wt[128 * WBT_PITCH];
    int t = threadIdx.x;
    for (int i = t; i < 2176; i += 256)
        ((uint4*)Wt)[i] = ((const uint4*)Wbt)[i];
    __syncthreads();

    int wv = t >> 6, l = t & 63;
    int m = l & 15;
    int kg = l >> 4;
    int row = blockIdx.x * 64 + wv * 16 + m;
    bool valid = row < nrows;
    const float* xr = X + (long)row * 128;

    f32x4 acc[8];
#pragma unroll
    for (int n = 0; n < 8; ++n) acc[n] = (f32x4){0.f, 0.f, 0.f, 0.f};

#pragma unroll
    for (int t4 = 0; t4 < 4; ++t4) {
        int k0 = t4 * 32 + kg * 8;
        float xv[8];
        if (valid) {
            float4 u0 = *(const float4*)(xr + k0);
            float4 u1 = *(const float4*)(xr + k0 + 4);
            if (BN) {
                float4 s0 = *(const float4*)(coef + k0);
                float4 s1 = *(const float4*)(coef + k0 + 4);
                float4 h0 = *(const float4*)(coef + 128 + k0);
                float4 h1 = *(const float4*)(coef + 128 + k0 + 4);
                u0.x = fmaxf(u0.x * s0.x + h0.x, 0.f);
                u0.y = fmaxf(u0.y * s0.y + h0.y, 0.f);
                u0.z = fmaxf(u0.z * s0.z + h0.z, 0.f);
                u0.w = fmaxf(u0.w * s0.w + h0.w, 0.f);
                u1.x = fmaxf(u1.x * s1.x + h1.x, 0.f);
                u1.y = fmaxf(u1.y * s1.y + h1.y, 0.f);
                u1.z = fmaxf(u1.z * s1.z + h1.z, 0.f);
                u1.w = fmaxf(u1.w * s1.w + h1.w, 0.f);
            }
            xv[0] = u0.x; xv[1] = u0.y; xv[2] = u0.z; xv[3] = u0.w;
            xv[4] = u1.x; xv[5] = u1.y; xv[6] = u1.z; xv[7] = u1.w;
        } else {
#pragma unroll
            for (int j = 0; j < 8; ++j) xv[j] = 0.f;
        }
        union { ushort u[8]; bf16x8 v; } A;
#pragma unroll
        for (int j = 0; j < 8; ++j) A.u[j] = f2bf(xv[j]);

#pragma unroll
        for (int n = 0; n < 8; ++n) {
            bf16x8 b = *(const bf16x8*)(&Wt[(n * 16 + m) * WBT_PITCH + k0]);
            acc[n] = __builtin_amdgcn_mfma_f32_16x16x32_bf16(A.v, b, acc[n], 0, 0, 0);
        }
    }

    int srow0 = blockIdx.x * 64 + wv * 16 + kg * 4;
#pragma unroll
    for (int n = 0; n < 8; ++n)
#pragma unroll
        for (int r = 0; r < 4; ++r) {
            int rr = srow0 + r;
            if (rr < nrows) Hb[(long)rr * 128 + n * 16 + m] = f2bf(acc[n][r]);
        }
}

// ---------------- aggregation: quarter-wave per edge (16 lanes x 8 ch) -----
__global__ __launch_bounds__(256) void k_agg(const ushort* __restrict__ Hb,
                                             const int* __restrict__ rowptr,
                                             const int* __restrict__ csr,
                                             const float* __restrict__ csrd,
                                             const float* __restrict__ dinv,
                                             const float* __restrict__ bias,
                                             float* __restrict__ OUT) {
    int wave = threadIdx.x >> 6, lane = threadIdx.x & 63;
    int v = blockIdx.x * 4 + wave;
    if (v >= N_NODES) return;
    int q = lane >> 4, ql = lane & 15;
    int c = ql * 8;
    float dv = dinv[v];
    int e0 = rowptr[v];
    int deg = rowptr[v + 1] - e0;
    // issue self-row gather early (q==0 lanes only; hides under edge loop)
    uint4 qv_self = make_uint4(0u, 0u, 0u, 0u);
    if (q == 0) qv_self = *(const uint4*)(Hb + (long)v * 128 + c);
    float a0 = 0.f, a1 = 0.f, a2 = 0.f, a3 = 0.f;
    float a4 = 0.f, a5 = 0.f, a6 = 0.f, a7 = 0.f;

    for (int base = 0; base < deg; base += 64) {
        int mye = base + lane;
        int idx = 0; float dvi = 0.f;
        if (mye < deg) { idx = csr[e0 + mye]; dvi = csrd[e0 + mye]; }
        int n = min(64, deg - base);
        int P = (n + 3) >> 2;
        int p = 0;
#define EDGE(pp) { \
        int sl = 4 * (pp) + q; \
        int s = __shfl(idx, sl); \
        float cf = __shfl(dvi, sl) * dv; \
        uint4 qv = *(const uint4*)(Hb + (long)s * 128 + c); \
        a0 += cf * bf2f(qv.x & 0xFFFFu); \
        a1 += cf * bf2f(qv.x >> 16); \
        a2 += cf * bf2f(qv.y & 0xFFFFu); \
        a3 += cf * bf2f(qv.y >> 16); \
        a4 += cf * bf2f(qv.z & 0xFFFFu); \
        a5 += cf * bf2f(qv.z >> 16); \
        a6 += cf * bf2f(qv.w & 0xFFFFu); \
        a7 += cf * bf2f(qv.w >> 16); }
        for (; p + 4 <= P; p += 4) { EDGE(p) EDGE(p + 1) EDGE(p + 2) EDGE(p + 3) }
        for (; p < P; ++p) { EDGE(p) }
#undef EDGE
    }
    a0 += __shfl_xor(a0, 16); a0 += __shfl_xor(a0, 32);
    a1 += __shfl_xor(a1, 16); a1 += __shfl_xor(a1, 32);
    a2 += __shfl_xor(a2, 16); a2 += __shfl_xor(a2, 32);
    a3 += __shfl_xor(a3, 16); a3 += __shfl_xor(a3, 32);
    a4 += __shfl_xor(a4, 16); a4 += __shfl_xor(a4, 32);
    a5 += __shfl_xor(a5, 16); a5 += __shfl_xor(a5, 32);
    a6 += __shfl_xor(a6, 16); a6 += __shfl_xor(a6, 32);
    a7 += __shfl_xor(a7, 16); a7 += __shfl_xor(a7, 32);
    if (q == 0) {
        float cs = dv * dv;
        float4 b0 = *(const float4*)(bias + c);
        float4 b1 = *(const float4*)(bias + c + 4);
        float4 o0, o1;
        o0.x = a0 + cs * bf2f(qv_self.x & 0xFFFFu) + b0.x;
        o0.y = a1 + cs * bf2f(qv_self.x >> 16) + b0.y;
        o0.z = a2 + cs * bf2f(qv_self.y & 0xFFFFu) + b0.z;
        o0.w = a3 + cs * bf2f(qv_self.y >> 16) + b0.w;
        o1.x = a4 + cs * bf2f(qv_self.z & 0xFFFFu) + b1.x;
        o1.y = a5 + cs * bf2f(qv_self.z >> 16) + b1.y;
        o1.z = a6 + cs * bf2f(qv_self.w & 0xFFFFu) + b1.z;
        o1.w = a7 + cs * bf2f(qv_self.w >> 16) + b1.w;
        *(float4*)(OUT + (long)v * 128 + c) = o0;
        *(float4*)(OUT + (long)v * 128 + c + 4) = o1;
    }
}

// ---------------- BN stats phase 1: per-block partials (no atomics) --------
__global__ __launch_bounds__(256) void k_bnstats(const float* __restrict__ X,
                                                 float* __restrict__ part) {
    int ch = threadIdx.x & 127;
    int half = threadIdx.x >> 7;
    float s = 0.f, q = 0.f;
    for (int v = blockIdx.x * 2 + half; v < N_NODES; v += BN_BLOCKS * 2) {
        float x = X[(long)v * 128 + ch];
        s += x;
        q += x * x;
    }
    __shared__ float sh[256];
    sh[threadIdx.x] = s;
    __syncthreads();
    float s2 = (half == 0) ? s + sh[threadIdx.x + 128] : 0.f;
    __syncthreads();
    sh[threadIdx.x] = q;
    __syncthreads();
    if (half == 0) {
        float q2 = q + sh[threadIdx.x + 128];
        part[blockIdx.x * 256 + ch] = s2;
        part[blockIdx.x * 256 + 128 + ch] = q2;
    }
}

// ---------------- BN stats phase 2: 1024-thr fixed-order reduce + coef -----
__global__ __launch_bounds__(1024) void k_bnred(const float* __restrict__ part,
                                                const float* __restrict__ g,
                                                const float* __restrict__ be,
                                                float* __restrict__ coef) {
    __shared__ float sh[4][256];
    int t = threadIdx.x;
    int st = t & 255;                 // stat-channel slot (0..255)
    int quarter = t >> 8;             // 0..3
    float acc = 0.f;
    int b0 = quarter * (BN_BLOCKS / 4);
    for (int b = b0; b < b0 + BN_BLOCKS / 4; ++b) acc += part[b * 256 + st];
    sh[quarter][st] = acc;
    __syncthreads();
    if (quarter == 0) {
        float total = ((sh[0][st] + sh[1][st]) + sh[2][st]) + sh[3][st];
        sh[0][st] = total;
    }
    __syncthreads();
    if (t < 128) {
        int ch = t;
        float inv_n = 1.0f / (float)N_NODES;
        float mean = sh[0][ch] * inv_n;
        float var = sh[0][128 + ch] * inv_n - mean * mean;
        float sc = g[ch] * rsqrtf(var + BN_EPS);
        coef[ch] = sc;
        coef[128 + ch] = be[ch] - mean * sc;
    }
}

// ---------------- pooling + MLP fused: 1024 thr, 32-way node parallel ------
__global__ __launch_bounds__(1024) void k_poolmlp(const float* __restrict__ X,
                                                  const int* __restrict__ batch,
                                                  const float* __restrict__ coef,
                                                  const float* __restrict__ w1,
                                                  const float* __restrict__ b1,
                                                  const float* __restrict__ w2,
                                                  const float* __restrict__ b2,
                                                  float* __restrict__ out) {
    __shared__ int bounds[2];
    __shared__ float red[32][128];   // [way][ch], 16 KB
    __shared__ float h[256];
    __shared__ float h1[128];
    int g = blockIdx.x, t = threadIdx.x;
    if (t < 2) {
        int target = g + t;
        int lo = 0, hi = N_NODES;
        while (lo < hi) {
            int mid = (lo + hi) >> 1;
            if (batch[mid] < target) lo = mid + 1; else hi = mid;
        }
        bounds[t] = lo;
    }
    __syncthreads();
    int start = bounds[0], end = bounds[1];
    int way = t >> 5;              // 0..31
    int cg = (t & 31) << 2;        // channel group base 0,4,...,124
    float4 sc = *(const float4*)(coef + cg);
    float4 sh = *(const float4*)(coef + 128 + cg);
    float4 acc = make_float4(0.f, 0.f, 0.f, 0.f);
    for (int v = start + way; v < end; v += 32) {
        float4 xv = *(const float4*)(X + (long)v * 128 + cg);
        acc.x += fmaxf(xv.x * sc.x + sh.x, 0.f);
        acc.y += fmaxf(xv.y * sc.y + sh.y, 0.f);
        acc.z += fmaxf(xv.z * sc.z + sh.z, 0.f);
        acc.w += fmaxf(xv.w * sc.w + sh.w, 0.f);
    }
    *(float4*)(&red[way][cg]) = acc;
    __syncthreads();
#pragma unroll
    for (int off = 16; off > 0; off >>= 1) {
        if (way < off) {
            float4 a = *(float4*)(&red[way][cg]);
            float4 b = *(float4*)(&red[way + off][cg]);
            a.x += b.x; a.y += b.y; a.z += b.z; a.w += b.w;
            *(float4*)(&red[way][cg]) = a;
        }
        __syncthreads();
    }
    if (way == 0) {
        float4 s = *(float4*)(&red[0][cg]);
        float inv = 1.0f / fmaxf((float)(end - start), 1.0f);
        h[cg] = s.x * inv; h[cg + 1] = s.y * inv;
        h[cg + 2] = s.z * inv; h[cg + 3] = s.w * inv;     // mean
        h[128 + cg] = s.x; h[128 + cg + 1] = s.y;
        h[128 + cg + 2] = s.z; h[128 + cg + 3] = s.w;     // sum
    }
    __syncthreads();
    int o1 = t & 127, w8 = t >> 7;   // w8: 0..7
    float a = 0.f;
    int i0 = w8 * 32;
#pragma unroll 8
    for (int i = i0; i < i0 + 32; ++i) a += h[i] * w1[i * 128 + o1];
    red[w8][o1] = a;                 // reuse red as [8][128]
    __syncthreads();
    if (w8 == 0) {
        float s = b1[o1];
#pragma unroll
        for (int k = 0; k < 8; ++k) s += red[k][o1];
        h1[o1] = fmaxf(s, 0.f);
    }
    __syncthreads();
    if (t < OUT_CH) {
        float o = b2[t];
#pragma unroll 4
        for (int j = 0; j < 128; ++j) o += h1[j] * w2[j * OUT_CH + t];
        out[g * OUT_CH + t] = o;
    }
}

extern "C" void kernel_launch(void* const* d_in, const int* in_sizes, int n_in,
                              void* d_out, int out_size, void* d_ws, size_t ws_size,
                              hipStream_t stream) {
    const float* x = (const float*)d_in[0];
    const int* ei = (const int*)d_in[1];
    const int* batch = (const int*)d_in[2];
    const float* W[3] = {(const float*)d_in[3], (const float*)d_in[7], (const float*)d_in[11]};
    const float* b[3] = {(const float*)d_in[4], (const float*)d_in[8], (const float*)d_in[12]};
    const float* gm[3] = {(const float*)d_in[5], (const float*)d_in[9], (const float*)d_in[13]};
    const float* be[3] = {(const float*)d_in[6], (const float*)d_in[10], (const float*)d_in[14]};
    const float* w1 = (const float*)d_in[15];
    const float* b1 = (const float*)d_in[16];
    const float* w2 = (const float*)d_in[17];
    const float* b2 = (const float*)d_in[18];
    float* out = (float*)d_out;

    float* ws = (float*)d_ws;
    ushort* Hb = (ushort*)(ws + OFF_H);
    float* bnpart = ws + OFF_BNPART;
    float* csrd = ws + OFF_CSRD;
    ushort* Wbt = (ushort*)(ws + OFF_WBT);
    float* AGG = ws + OFF_AGG;
    int2* bucketBuf = (int2*)(ws + OFF_AGG);
    int* rowptr = (int*)(ws + OFF_ROWPTR);
    int* csr = (int*)(ws + OFF_CSR);
    float* dinv = ws + OFF_DINV;
    float* bncoef = ws + OFF_BNCOEF;
    int* bcnt = (int*)(ws + OFF_BCNT);

    const int nb_node4 = (N_NODES + 3) / 4;     // 12500

    hipLaunchKernelGGL(k_prep, dim3(192), dim3(256), 0, stream,
                       W[0], W[1], W[2], Wbt, bcnt);
    hipLaunchKernelGGL(k_bucket, dim3(784), dim3(256), 0, stream, ei, bcnt, bucketBuf);
    hipLaunchKernelGGL(k_csrbuild, dim3(NBUCKET), dim3(512), 0, stream,
                       bucketBuf, bcnt, rowptr, csr, dinv);
    hipLaunchKernelGGL(k_sortseg, dim3(nb_node4), dim3(256), 0, stream,
                       rowptr, csr, dinv, csrd);

    const int gemm_blocks = (N_NODES + 63) / 64;  // 782
    for (int layer = 0; layer < 3; ++layer) {
        const float* cur_x = (layer == 0) ? x : AGG;
        const ushort* wbt_l = Wbt + layer * 128 * WBT_PITCH;
        if (layer == 0) {
            hipLaunchKernelGGL(k_gemm<0>, dim3(gemm_blocks), dim3(256), 0, stream,
                               cur_x, wbt_l, Hb, (const float*)nullptr, N_NODES);
        } else {
            hipLaunchKernelGGL(k_gemm<1>, dim3(gemm_blocks), dim3(256), 0, stream,
                               cur_x, wbt_l, Hb, bncoef, N_NODES);
        }
        hipLaunchKernelGGL(k_agg, dim3(nb_node4), dim3(256), 0, stream,
                           Hb, rowptr, csr, csrd, dinv, b[layer], AGG);
        hipLaunchKernelGGL(k_bnstats, dim3(BN_BLOCKS), dim3(256), 0, stream, AGG, bnpart);
        hipLaunchKernelGGL(k_bnred, dim3(1), dim3(1024), 0, stream,
                           bnpart, gm[layer], be[layer], bncoef);
    }

    hipLaunchKernelGGL(k_poolmlp, dim3(N_GRAPHS), dim3(1024), 0, stream,
                       AGG, batch, bncoef, w1, b1, w2, b2, out);
}